// Round 1
// baseline (991.765 us; speedup 1.0000x reference)
//
#include <hip/hip_runtime.h>

// ProteinMPNN encoder layer, MI355X/gfx950.
// Strategy: all five matmuls run as bf16 16x16x32 MFMA with fp32 accum;
// residuals + LayerNorms stay fp32. Weights pre-transposed to W^T[n][k] bf16
// so B-fragments are contiguous 16B loads. Node/edge message kernels process
// 2 nodes (96 edge rows) per 256-thread block, waves split 2M x 2N.
// LDS A-tile stride 264 shorts (528B: 16B-aligned, 132 dw = 4 mod 32 -> clean
// banking); x1/x2 (stride 136) and the fp32 msg buffer overlay the A region.

typedef __attribute__((ext_vector_type(8))) short short8;
typedef __attribute__((ext_vector_type(4))) float f32x4;

#define MFMA16(a,b,c) __builtin_amdgcn_mfma_f32_16x16x32_bf16((a),(b),(c),0,0,0)

#define L_SEQ 2048
#define K_NBR 48
#define H_DIM 128

__device__ __forceinline__ unsigned short f2bf(float x){
  unsigned int u = __float_as_uint(x);
  unsigned int r = (u + 0x7fffu + ((u >> 16) & 1u)) >> 16;
  return (unsigned short)r;
}
__device__ __forceinline__ float bflo(unsigned int u){ return __uint_as_float(u << 16); }
__device__ __forceinline__ float bfhi(unsigned int u){ return __uint_as_float(u & 0xffff0000u); }

// tanh-approx GELU via hw exp2 (max dev from erf-GELU ~3e-4, far below bf16 noise)
__device__ __forceinline__ float gelu_f(float x){
  float t = fmaf(x * x, 0.044715f, 1.0f);
  float e = exp2f(-2.3022082f * x * t);   // 2*sqrt(2/pi)*log2(e)
  return x / (1.0f + e);
}

// ---------- K0a: Wt[c][r] = bf16(W[r][c]) ----------
__global__ void k_wt(const float* __restrict__ in, unsigned short* __restrict__ out,
                     int R, int C){
  int o = blockIdx.x * 256 + threadIdx.x;
  int c = o / R, r = o - c * R;
  out[o] = f2bf(in[r * C + c]);
}

// ---------- K0b: h_V -> bf16 ----------
__global__ void k_cvt16(const float* __restrict__ in, unsigned short* __restrict__ out){
  int i = blockIdx.x * 256 + threadIdx.x;       // float4 index
  float4 v = ((const float4*)in)[i];
  uint2 p;
  p.x = (unsigned)f2bf(v.x) | ((unsigned)f2bf(v.y) << 16);
  p.y = (unsigned)f2bf(v.z) | ((unsigned)f2bf(v.w) << 16);
  ((uint2*)out)[i] = p;
}

// ---------- K1: node message MLP + sum + LN1 ----------
__global__ __launch_bounds__(256, 3) void k_node(
  const float* __restrict__ hV, const float* __restrict__ hE,
  const unsigned short* __restrict__ hV16,
  const int* __restrict__ Eidx, const float* __restrict__ maskA,
  const unsigned short* __restrict__ Wt1, const float* __restrict__ b1,
  const unsigned short* __restrict__ Wt2, const float* __restrict__ b2,
  const unsigned short* __restrict__ Wt3, const float* __restrict__ b3,
  const float* __restrict__ n1g, const float* __restrict__ n1b,
  float* __restrict__ v32, unsigned short* __restrict__ v16)
{
  __shared__ __align__(16) short Abuf[26112];   // 52224 B: A(264) / X1,X2(136)
  __shared__ float hv[2][128];
  __shared__ float sbias[2][128];               // reused as dh after layer-1 use
  float* dhb = &sbias[0][0];

  const int tid = threadIdx.x;
  const int n0 = blockIdx.x * 2;
  const int b  = n0 >> 11;
  const int l0 = n0 & 2047;
  const int node_base = b * L_SEQ + l0;

  { int s = tid >> 7, c = tid & 127;
    hv[s][c] = hV[(size_t)(node_base + s) * H_DIM + c]; }
  __syncthreads();

  // ---- stage A: cols 0..127 = h_E (f32->bf16), 128..255 = gathered h_V (bf16)
  for (int s = 0; s < 2; ++s) {
    const float4* srcE = (const float4*)(hE + (size_t)(node_base + s) * K_NBR * H_DIM);
    const int* eip = Eidx + (size_t)(node_base + s) * K_NBR;
    for (int i = tid; i < 1536; i += 256) {
      float4 v = srcE[i];
      int r = s * 48 + (i >> 5);
      int c = (i & 31) << 2;
      uint2 p;
      p.x = (unsigned)f2bf(v.x) | ((unsigned)f2bf(v.y) << 16);
      p.y = (unsigned)f2bf(v.z) | ((unsigned)f2bf(v.w) << 16);
      *(uint2*)&Abuf[r * 264 + c] = p;
    }
    for (int i = tid; i < 1536; i += 256) {
      int r0 = i >> 5;
      int c = (i & 31) << 2;
      int e = eip[r0];
      const uint2* srcn = (const uint2*)(hV16 + (size_t)(b * L_SEQ + e) * H_DIM);
      *(uint2*)&Abuf[(s * 48 + r0) * 264 + 128 + c] = srcn[i & 31];
    }
  }
  // ---- sbias[s][c] = b1[c] + sum_j hv[s][j] * W1[j][c]  (self third of concat)
  { int s = tid >> 7, c = tid & 127;
    float acc = b1[c];
    const unsigned int* w = (const unsigned int*)(Wt1 + (size_t)c * 384);
    const float4* h4 = (const float4*)hv[s];
    #pragma unroll 8
    for (int j = 0; j < 32; ++j) {
      float4 hh = h4[j];
      unsigned int w0 = w[2 * j], w1 = w[2 * j + 1];
      acc = fmaf(hh.x, bflo(w0), acc);
      acc = fmaf(hh.y, bfhi(w0), acc);
      acc = fmaf(hh.z, bflo(w1), acc);
      acc = fmaf(hh.w, bfhi(w1), acc);
    }
    sbias[s][c] = acc;
  }
  __syncthreads();

  const int wid = tid >> 6, lane = tid & 63;
  const int wm = wid >> 1, wn = wid & 1;
  const int lr = lane & 15, lg = lane >> 4;
  const int arow = wm * 48 + lr;
  const int kele = lg * 8;

  f32x4 zero = {0.f, 0.f, 0.f, 0.f};
  f32x4 acc[3][4];
  #pragma unroll
  for (int t = 0; t < 3; ++t)
    #pragma unroll
    for (int n = 0; n < 4; ++n) acc[t][n] = zero;

  // ---- layer 1 (K=256)
  #pragma unroll 2
  for (int kk = 0; kk < 8; ++kk) {
    short8 a0 = *(const short8*)&Abuf[(arow     ) * 264 + kk * 32 + kele];
    short8 a1 = *(const short8*)&Abuf[(arow + 16) * 264 + kk * 32 + kele];
    short8 a2 = *(const short8*)&Abuf[(arow + 32) * 264 + kk * 32 + kele];
    #pragma unroll
    for (int n = 0; n < 4; ++n) {
      short8 bf = *(const short8*)(const void*)(Wt1 + (size_t)(wn * 64 + n * 16 + lr) * 384 + 128 + kk * 32 + kele);
      acc[0][n] = MFMA16(a0, bf, acc[0][n]);
      acc[1][n] = MFMA16(a1, bf, acc[1][n]);
      acc[2][n] = MFMA16(a2, bf, acc[2][n]);
    }
  }
  __syncthreads();                       // all A reads done; region becomes X1/X2
  #pragma unroll
  for (int t = 0; t < 3; ++t)
    #pragma unroll
    for (int n = 0; n < 4; ++n) {
      int col = wn * 64 + n * 16 + lr;
      float sb = sbias[wm][col];
      #pragma unroll
      for (int r = 0; r < 4; ++r) {
        int row = wm * 48 + t * 16 + lg * 4 + r;
        Abuf[row * 136 + col] = (short)f2bf(gelu_f(acc[t][n][r] + sb));
      }
    }
  __syncthreads();                       // X1 ready

  // ---- layer 2 (K=128)
  #pragma unroll
  for (int t = 0; t < 3; ++t)
    #pragma unroll
    for (int n = 0; n < 4; ++n) acc[t][n] = zero;
  #pragma unroll
  for (int kk = 0; kk < 4; ++kk) {
    short8 a0 = *(const short8*)&Abuf[(arow     ) * 136 + kk * 32 + kele];
    short8 a1 = *(const short8*)&Abuf[(arow + 16) * 136 + kk * 32 + kele];
    short8 a2 = *(const short8*)&Abuf[(arow + 32) * 136 + kk * 32 + kele];
    #pragma unroll
    for (int n = 0; n < 4; ++n) {
      short8 bf = *(const short8*)(const void*)(Wt2 + (size_t)(wn * 64 + n * 16 + lr) * 128 + kk * 32 + kele);
      acc[0][n] = MFMA16(a0, bf, acc[0][n]);
      acc[1][n] = MFMA16(a1, bf, acc[1][n]);
      acc[2][n] = MFMA16(a2, bf, acc[2][n]);
    }
  }
  #pragma unroll
  for (int t = 0; t < 3; ++t)            // X2 at +13056 shorts (disjoint from X1)
    #pragma unroll
    for (int n = 0; n < 4; ++n) {
      int col = wn * 64 + n * 16 + lr;
      float bb = b2[col];
      #pragma unroll
      for (int r = 0; r < 4; ++r) {
        int row = wm * 48 + t * 16 + lg * 4 + r;
        Abuf[13056 + row * 136 + col] = (short)f2bf(gelu_f(acc[t][n][r] + bb));
      }
    }
  __syncthreads();                       // X2 ready

  // ---- layer 3 (K=128) + mask + k-sum
  #pragma unroll
  for (int t = 0; t < 3; ++t)
    #pragma unroll
    for (int n = 0; n < 4; ++n) acc[t][n] = zero;
  #pragma unroll
  for (int kk = 0; kk < 4; ++kk) {
    short8 a0 = *(const short8*)&Abuf[13056 + (arow     ) * 136 + kk * 32 + kele];
    short8 a1 = *(const short8*)&Abuf[13056 + (arow + 16) * 136 + kk * 32 + kele];
    short8 a2 = *(const short8*)&Abuf[13056 + (arow + 32) * 136 + kk * 32 + kele];
    #pragma unroll
    for (int n = 0; n < 4; ++n) {
      short8 bf = *(const short8*)(const void*)(Wt3 + (size_t)(wn * 64 + n * 16 + lr) * 128 + kk * 32 + kele);
      acc[0][n] = MFMA16(a0, bf, acc[0][n]);
      acc[1][n] = MFMA16(a1, bf, acc[1][n]);
      acc[2][n] = MFMA16(a2, bf, acc[2][n]);
    }
  }
  const float* mrow = maskA + (size_t)(node_base + wm) * K_NBR;
  float mk[3][4];
  #pragma unroll
  for (int t = 0; t < 3; ++t)
    #pragma unroll
    for (int r = 0; r < 4; ++r) mk[t][r] = mrow[t * 16 + lg * 4 + r];
  float part[4];
  #pragma unroll
  for (int n = 0; n < 4; ++n) {
    int col = wn * 64 + n * 16 + lr;
    float bb = b3[col];
    float p = 0.f;
    #pragma unroll
    for (int t = 0; t < 3; ++t)
      #pragma unroll
      for (int r = 0; r < 4; ++r)
        p += (acc[t][n][r] + bb) * mk[t][r];
    part[n] = p;
  }
  #pragma unroll
  for (int n = 0; n < 4; ++n) {
    part[n] += __shfl_xor(part[n], 16);
    part[n] += __shfl_xor(part[n], 32);
  }
  if (lane < 16) {
    #pragma unroll
    for (int n = 0; n < 4; ++n)
      dhb[wm * 128 + wn * 64 + n * 16 + lane] = part[n] * (1.f / 30.f);
  }
  __syncthreads();

  // ---- LN1 -> v (fp32 + bf16)
  if (wid < 2) {
    int s = wid;
    int node = node_base + s;
    float u0 = hv[s][lane]      + dhb[s * 128 + lane];
    float u1 = hv[s][lane + 64] + dhb[s * 128 + lane + 64];
    float s1 = u0 + u1, s2 = u0 * u0 + u1 * u1;
    #pragma unroll
    for (int off = 1; off < 64; off <<= 1) {
      s1 += __shfl_xor(s1, off);
      s2 += __shfl_xor(s2, off);
    }
    float mean = s1 * 0.0078125f;
    float var  = fmaf(s2, 0.0078125f, -mean * mean);
    float rs = rsqrtf(var + 1e-5f);
    float vv0 = (u0 - mean) * rs * n1g[lane]      + n1b[lane];
    float vv1 = (u1 - mean) * rs * n1g[lane + 64] + n1b[lane + 64];
    v32[(size_t)node * 128 + lane]      = vv0;
    v32[(size_t)node * 128 + lane + 64] = vv1;
    v16[(size_t)node * 128 + lane]      = f2bf(vv0);
    v16[(size_t)node * 128 + lane + 64] = f2bf(vv1);
  }
}

// ---------- K2a: xg = gelu(v @ Wg_in + bg_in), 32 rows/block ----------
__global__ __launch_bounds__(256) void k_ffn1(
  const unsigned short* __restrict__ v16, const unsigned short* __restrict__ Wtgi,
  const float* __restrict__ bgi, unsigned short* __restrict__ xg)
{
  __shared__ __align__(16) short Av[32 * 136];
  const int tid = threadIdx.x;
  const int row0 = blockIdx.x * 32;
  const uint2* src = (const uint2*)(v16 + (size_t)row0 * 128);
  for (int i = tid; i < 1024; i += 256) {
    int r = i >> 5, c = (i & 31) << 2;
    *(uint2*)&Av[r * 136 + c] = src[i];
  }
  __syncthreads();
  const int wid = tid >> 6, lane = tid & 63;
  const int lr = lane & 15, lg = lane >> 4, kele = lg * 8;
  f32x4 zero = {0.f, 0.f, 0.f, 0.f};
  f32x4 acc[2][8];
  #pragma unroll
  for (int t = 0; t < 2; ++t)
    #pragma unroll
    for (int n = 0; n < 8; ++n) acc[t][n] = zero;
  #pragma unroll
  for (int kk = 0; kk < 4; ++kk) {
    short8 a0 = *(const short8*)&Av[(lr     ) * 136 + kk * 32 + kele];
    short8 a1 = *(const short8*)&Av[(lr + 16) * 136 + kk * 32 + kele];
    #pragma unroll
    for (int n = 0; n < 8; ++n) {
      short8 bf = *(const short8*)(const void*)(Wtgi + (size_t)(wid * 128 + n * 16 + lr) * 128 + kk * 32 + kele);
      acc[0][n] = MFMA16(a0, bf, acc[0][n]);
      acc[1][n] = MFMA16(a1, bf, acc[1][n]);
    }
  }
  #pragma unroll
  for (int t = 0; t < 2; ++t)
    #pragma unroll
    for (int n = 0; n < 8; ++n) {
      int col = wid * 128 + n * 16 + lr;
      float bb = bgi[col];
      #pragma unroll
      for (int r = 0; r < 4; ++r) {
        int row = row0 + t * 16 + lg * 4 + r;
        xg[(size_t)row * 512 + col] = f2bf(gelu_f(acc[t][n][r] + bb));
      }
    }
}

// ---------- K2b: h_Vnew = mask_V * LN2(v + xg @ Wg_out + bg_out) ----------
__global__ __launch_bounds__(256) void k_ffn2(
  const unsigned short* __restrict__ xg, const unsigned short* __restrict__ Wtgo,
  const float* __restrict__ bgo, const float* __restrict__ v32,
  const float* __restrict__ n2g, const float* __restrict__ n2b,
  const float* __restrict__ maskV, float* __restrict__ outV)
{
  __shared__ __align__(16) short Axg[32 * 520];
  __shared__ float U[32 * 132];
  const int tid = threadIdx.x;
  const int row0 = blockIdx.x * 32;
  const uint2* src = (const uint2*)(xg + (size_t)row0 * 512);
  for (int i = tid; i < 4096; i += 256) {
    int r = i >> 7, c = (i & 127) << 2;
    *(uint2*)&Axg[r * 520 + c] = src[i];
  }
  __syncthreads();
  const int wid = tid >> 6, lane = tid & 63;
  const int lr = lane & 15, lg = lane >> 4, kele = lg * 8;
  f32x4 zero = {0.f, 0.f, 0.f, 0.f};
  f32x4 acc[2][2];
  #pragma unroll
  for (int t = 0; t < 2; ++t)
    #pragma unroll
    for (int n = 0; n < 2; ++n) acc[t][n] = zero;
  #pragma unroll 4
  for (int kk = 0; kk < 16; ++kk) {
    short8 a0 = *(const short8*)&Axg[(lr     ) * 520 + kk * 32 + kele];
    short8 a1 = *(const short8*)&Axg[(lr + 16) * 520 + kk * 32 + kele];
    #pragma unroll
    for (int n = 0; n < 2; ++n) {
      short8 bf = *(const short8*)(const void*)(Wtgo + (size_t)(wid * 32 + n * 16 + lr) * 512 + kk * 32 + kele);
      acc[0][n] = MFMA16(a0, bf, acc[0][n]);
      acc[1][n] = MFMA16(a1, bf, acc[1][n]);
    }
  }
  #pragma unroll
  for (int t = 0; t < 2; ++t)
    #pragma unroll
    for (int n = 0; n < 2; ++n) {
      int col = wid * 32 + n * 16 + lr;
      float bb = bgo[col];
      #pragma unroll
      for (int r = 0; r < 4; ++r) {
        int row = t * 16 + lg * 4 + r;
        U[row * 132 + col] = acc[t][n][r] + bb + v32[(size_t)(row0 + row) * 128 + col];
      }
    }
  __syncthreads();
  int r = tid >> 3, sub = tid & 7;
  const float* Ur = &U[r * 132 + sub * 16];
  float u[16]; float s1 = 0.f, s2 = 0.f;
  #pragma unroll
  for (int i = 0; i < 16; ++i) { u[i] = Ur[i]; s1 += u[i]; s2 += u[i] * u[i]; }
  s1 += __shfl_xor(s1, 1); s1 += __shfl_xor(s1, 2); s1 += __shfl_xor(s1, 4);
  s2 += __shfl_xor(s2, 1); s2 += __shfl_xor(s2, 2); s2 += __shfl_xor(s2, 4);
  float mean = s1 * 0.0078125f;
  float var  = fmaf(s2, 0.0078125f, -mean * mean);
  float rs = rsqrtf(var + 1e-5f);
  int node = row0 + r;
  float mv = maskV[node];
  float* dst = outV + (size_t)node * 128 + sub * 16;
  #pragma unroll
  for (int i = 0; i < 16; ++i) {
    int c = sub * 16 + i;
    dst[i] = ((u[i] - mean) * rs * n2g[c] + n2b[c]) * mv;
  }
}

// ---------- K3: edge message MLP + residual + LN3 ----------
__global__ __launch_bounds__(256, 3) void k_edge(
  const float* __restrict__ hE, const int* __restrict__ Eidx,
  const float* __restrict__ hVn,
  const unsigned short* __restrict__ Wt11, const float* __restrict__ b11,
  const unsigned short* __restrict__ Wt12, const float* __restrict__ b12,
  const unsigned short* __restrict__ Wt13, const float* __restrict__ b13,
  const float* __restrict__ n3g, const float* __restrict__ n3b,
  float* __restrict__ outE)
{
  __shared__ __align__(16) short Abuf[26112];
  __shared__ float hv[2][128];
  __shared__ float sbias[2][128];     // later reused for n3g/n3b
  const int tid = threadIdx.x;
  const int n0 = blockIdx.x * 2;
  const int b  = n0 >> 11;
  const int l0 = n0 & 2047;
  const int node_base = b * L_SEQ + l0;

  { int s = tid >> 7, c = tid & 127;
    hv[s][c] = hVn[(size_t)(node_base + s) * H_DIM + c]; }
  __syncthreads();

  for (int s = 0; s < 2; ++s) {
    const float4* srcE = (const float4*)(hE + (size_t)(node_base + s) * K_NBR * H_DIM);
    const int* eip = Eidx + (size_t)(node_base + s) * K_NBR;
    for (int i = tid; i < 1536; i += 256) {
      float4 v = srcE[i];
      int r = s * 48 + (i >> 5);
      int c = (i & 31) << 2;
      uint2 p;
      p.x = (unsigned)f2bf(v.x) | ((unsigned)f2bf(v.y) << 16);
      p.y = (unsigned)f2bf(v.z) | ((unsigned)f2bf(v.w) << 16);
      *(uint2*)&Abuf[r * 264 + c] = p;
    }
    for (int i = tid; i < 1536; i += 256) {
      int r0 = i >> 5;
      int c = (i & 31) << 2;
      int e = eip[r0];
      const float4* srcn = (const float4*)(hVn + (size_t)(b * L_SEQ + e) * H_DIM);
      float4 v = srcn[i & 31];
      uint2 p;
      p.x = (unsigned)f2bf(v.x) | ((unsigned)f2bf(v.y) << 16);
      p.y = (unsigned)f2bf(v.z) | ((unsigned)f2bf(v.w) << 16);
      *(uint2*)&Abuf[(s * 48 + r0) * 264 + 128 + c] = p;
    }
  }
  { int s = tid >> 7, c = tid & 127;
    float acc = b11[c];
    const unsigned int* w = (const unsigned int*)(Wt11 + (size_t)c * 384);
    const float4* h4 = (const float4*)hv[s];
    #pragma unroll 8
    for (int j = 0; j < 32; ++j) {
      float4 hh = h4[j];
      unsigned int w0 = w[2 * j], w1 = w[2 * j + 1];
      acc = fmaf(hh.x, bflo(w0), acc);
      acc = fmaf(hh.y, bfhi(w0), acc);
      acc = fmaf(hh.z, bflo(w1), acc);
      acc = fmaf(hh.w, bfhi(w1), acc);
    }
    sbias[s][c] = acc;
  }
  __syncthreads();

  const int wid = tid >> 6, lane = tid & 63;
  const int wm = wid >> 1, wn = wid & 1;
  const int lr = lane & 15, lg = lane >> 4;
  const int arow = wm * 48 + lr;
  const int kele = lg * 8;

  f32x4 zero = {0.f, 0.f, 0.f, 0.f};
  f32x4 acc[3][4];
  #pragma unroll
  for (int t = 0; t < 3; ++t)
    #pragma unroll
    for (int n = 0; n < 4; ++n) acc[t][n] = zero;

  #pragma unroll 2
  for (int kk = 0; kk < 8; ++kk) {
    short8 a0 = *(const short8*)&Abuf[(arow     ) * 264 + kk * 32 + kele];
    short8 a1 = *(const short8*)&Abuf[(arow + 16) * 264 + kk * 32 + kele];
    short8 a2 = *(const short8*)&Abuf[(arow + 32) * 264 + kk * 32 + kele];
    #pragma unroll
    for (int n = 0; n < 4; ++n) {
      short8 bf = *(const short8*)(const void*)(Wt11 + (size_t)(wn * 64 + n * 16 + lr) * 384 + 128 + kk * 32 + kele);
      acc[0][n] = MFMA16(a0, bf, acc[0][n]);
      acc[1][n] = MFMA16(a1, bf, acc[1][n]);
      acc[2][n] = MFMA16(a2, bf, acc[2][n]);
    }
  }
  __syncthreads();
  #pragma unroll
  for (int t = 0; t < 3; ++t)
    #pragma unroll
    for (int n = 0; n < 4; ++n) {
      int col = wn * 64 + n * 16 + lr;
      float sb = sbias[wm][col];
      #pragma unroll
      for (int r = 0; r < 4; ++r) {
        int row = wm * 48 + t * 16 + lg * 4 + r;
        Abuf[row * 136 + col] = (short)f2bf(gelu_f(acc[t][n][r] + sb));
      }
    }
  __syncthreads();                       // X1 ready; sbias dead -> stage n3g/n3b
  if (tid < 128) {
    ((float*)sbias)[tid]       = n3g[tid];
    ((float*)sbias)[128 + tid] = n3b[tid];
  }

  #pragma unroll
  for (int t = 0; t < 3; ++t)
    #pragma unroll
    for (int n = 0; n < 4; ++n) acc[t][n] = zero;
  #pragma unroll
  for (int kk = 0; kk < 4; ++kk) {
    short8 a0 = *(const short8*)&Abuf[(arow     ) * 136 + kk * 32 + kele];
    short8 a1 = *(const short8*)&Abuf[(arow + 16) * 136 + kk * 32 + kele];
    short8 a2 = *(const short8*)&Abuf[(arow + 32) * 136 + kk * 32 + kele];
    #pragma unroll
    for (int n = 0; n < 4; ++n) {
      short8 bf = *(const short8*)(const void*)(Wt12 + (size_t)(wn * 64 + n * 16 + lr) * 128 + kk * 32 + kele);
      acc[0][n] = MFMA16(a0, bf, acc[0][n]);
      acc[1][n] = MFMA16(a1, bf, acc[1][n]);
      acc[2][n] = MFMA16(a2, bf, acc[2][n]);
    }
  }
  #pragma unroll
  for (int t = 0; t < 3; ++t)
    #pragma unroll
    for (int n = 0; n < 4; ++n) {
      int col = wn * 64 + n * 16 + lr;
      float bb = b12[col];
      #pragma unroll
      for (int r = 0; r < 4; ++r) {
        int row = wm * 48 + t * 16 + lg * 4 + r;
        Abuf[13056 + row * 136 + col] = (short)f2bf(gelu_f(acc[t][n][r] + bb));
      }
    }
  __syncthreads();

  #pragma unroll
  for (int t = 0; t < 3; ++t)
    #pragma unroll
    for (int n = 0; n < 4; ++n) acc[t][n] = zero;
  #pragma unroll
  for (int kk = 0; kk < 4; ++kk) {
    short8 a0 = *(const short8*)&Abuf[13056 + (arow     ) * 136 + kk * 32 + kele];
    short8 a1 = *(const short8*)&Abuf[13056 + (arow + 16) * 136 + kk * 32 + kele];
    short8 a2 = *(const short8*)&Abuf[13056 + (arow + 32) * 136 + kk * 32 + kele];
    #pragma unroll
    for (int n = 0; n < 4; ++n) {
      short8 bf = *(const short8*)(const void*)(Wt13 + (size_t)(wn * 64 + n * 16 + lr) * 128 + kk * 32 + kele);
      acc[0][n] = MFMA16(a0, bf, acc[0][n]);
      acc[1][n] = MFMA16(a1, bf, acc[1][n]);
      acc[2][n] = MFMA16(a2, bf, acc[2][n]);
    }
  }
  __syncthreads();                       // all X2 reads done; region becomes MSG
  float* MSG = (float*)&Abuf[0];         // stride 132 floats
  #pragma unroll
  for (int t = 0; t < 3; ++t)
    #pragma unroll
    for (int n = 0; n < 4; ++n) {
      int col = wn * 64 + n * 16 + lr;
      float bb = b13[col];
      #pragma unroll
      for (int r = 0; r < 4; ++r) {
        int row = wm * 48 + t * 16 + lg * 4 + r;
        MSG[row * 132 + col] = acc[t][n][r] + bb;
      }
    }
  __syncthreads();

  if (tid < 192) {
    int rr = tid >> 1, half = tid & 1;
    int s = rr >= 48 ? 1 : 0;
    int k = rr - s * 48;
    size_t ebase = ((size_t)(node_base + s) * 48 + k) * 128;
    const float4* he4 = (const float4*)(hE + ebase) + half * 16;
    const float4* m4  = (const float4*)&MSG[rr * 132] + half * 16;
    float s1 = 0.f, s2 = 0.f;
    #pragma unroll 4
    for (int i = 0; i < 16; ++i) {
      float4 a = he4[i]; float4 mm = m4[i];
      float x0 = a.x + mm.x, x1 = a.y + mm.y, x2 = a.z + mm.z, x3 = a.w + mm.w;
      s1 += x0 + x1 + x2 + x3;
      s2 += x0 * x0 + x1 * x1 + x2 * x2 + x3 * x3;
    }
    s1 += __shfl_xor(s1, 1);
    s2 += __shfl_xor(s2, 1);
    float mean = s1 * 0.0078125f;
    float var  = fmaf(s2, 0.0078125f, -mean * mean);
    float rs = rsqrtf(var + 1e-5f);
    const float* gb = (const float*)sbias;
    float4* dst = (float4*)(outE + ebase) + half * 16;
    #pragma unroll 4
    for (int i = 0; i < 16; ++i) {
      float4 a = he4[i]; float4 mm = m4[i];
      int c = half * 64 + i * 4;
      float4 o;
      o.x = (a.x + mm.x - mean) * rs * gb[c + 0] + gb[128 + c + 0];
      o.y = (a.y + mm.y - mean) * rs * gb[c + 1] + gb[128 + c + 1];
      o.z = (a.z + mm.z - mean) * rs * gb[c + 2] + gb[128 + c + 2];
      o.w = (a.w + mm.w - mean) * rs * gb[c + 3] + gb[128 + c + 3];
      dst[i] = o;
    }
  }
}

extern "C" void kernel_launch(void* const* d_in, const int* in_sizes, int n_in,
                              void* d_out, int out_size, void* d_ws, size_t ws_size,
                              hipStream_t stream) {
  const float* hV   = (const float*)d_in[0];
  const float* hE   = (const float*)d_in[1];
  const int*   Eidx = (const int*)d_in[2];
  const float* maskV= (const float*)d_in[3];
  const float* maskA= (const float*)d_in[4];
  const float* W1 = (const float*)d_in[5];  const float* b1 = (const float*)d_in[6];
  const float* W2 = (const float*)d_in[7];  const float* b2 = (const float*)d_in[8];
  const float* W3 = (const float*)d_in[9];  const float* b3 = (const float*)d_in[10];
  const float* W11= (const float*)d_in[11]; const float* b11= (const float*)d_in[12];
  const float* W12= (const float*)d_in[13]; const float* b12= (const float*)d_in[14];
  const float* W13= (const float*)d_in[15]; const float* b13= (const float*)d_in[16];
  const float* Wgi= (const float*)d_in[17]; const float* bgi= (const float*)d_in[18];
  const float* Wgo= (const float*)d_in[19]; const float* bgo= (const float*)d_in[20];
  const float* n1g= (const float*)d_in[21]; const float* n1b= (const float*)d_in[22];
  const float* n2g= (const float*)d_in[23]; const float* n2b= (const float*)d_in[24];
  const float* n3g= (const float*)d_in[25]; const float* n3b= (const float*)d_in[26];

  float* outV = (float*)d_out;
  float* outE = outV + (size_t)4 * 2048 * 128;   // h_E output region

  // d_ws: transposed bf16 weights only (590 KB) — must be outside d_out since
  // k_edge reads them while overwriting the whole h_E region.
  unsigned short* wsu  = (unsigned short*)d_ws;
  unsigned short* Wt1  = wsu + 0;
  unsigned short* Wt2  = wsu + 49152;
  unsigned short* Wt3  = wsu + 65536;
  unsigned short* Wt11 = wsu + 81920;
  unsigned short* Wt12 = wsu + 131072;
  unsigned short* Wt13 = wsu + 147456;
  unsigned short* Wtgi = wsu + 163840;
  unsigned short* Wtgo = wsu + 229376;

  // large intermediates live in the not-yet-written h_E output region
  // (all dead before k_edge starts writing it)
  char* scr = (char*)outE;
  unsigned short* hV16 = (unsigned short*)scr;              // 2 MB
  float*          v32  = (float*)(scr + (size_t)2097152);   // 4 MB
  unsigned short* v16  = (unsigned short*)(scr + (size_t)6291456); // 2 MB
  unsigned short* xg   = (unsigned short*)(scr + (size_t)8388608); // 8 MB

  k_wt<<<192, 256, 0, stream>>>(W1,  Wt1,  384, 128);
  k_wt<<<64,  256, 0, stream>>>(W2,  Wt2,  128, 128);
  k_wt<<<64,  256, 0, stream>>>(W3,  Wt3,  128, 128);
  k_wt<<<192, 256, 0, stream>>>(W11, Wt11, 384, 128);
  k_wt<<<64,  256, 0, stream>>>(W12, Wt12, 128, 128);
  k_wt<<<64,  256, 0, stream>>>(W13, Wt13, 128, 128);
  k_wt<<<256, 256, 0, stream>>>(Wgi, Wtgi, 128, 512);
  k_wt<<<256, 256, 0, stream>>>(Wgo, Wtgo, 512, 128);
  k_cvt16<<<1024, 256, 0, stream>>>(hV, hV16);

  k_node<<<4096, 256, 0, stream>>>(hV, hE, hV16, Eidx, maskA,
                                   Wt1, b1, Wt2, b2, Wt3, b3, n1g, n1b, v32, v16);
  k_ffn1<<<256, 256, 0, stream>>>(v16, Wtgi, bgi, xg);
  k_ffn2<<<256, 256, 0, stream>>>(xg, Wtgo, bgo, v32, n2g, n2b, maskV, outV);
  k_edge<<<4096, 256, 0, stream>>>(hE, Eidx, outV,
                                   Wt11, b11, Wt12, b12, Wt13, b13, n3g, n3b, outE);
}

// Round 3
// 826.589 us; speedup vs baseline: 1.1998x; 1.1998x over previous
//
#include <hip/hip_runtime.h>

// ProteinMPNN encoder layer, MI355X/gfx950.  R3 = R2 + k_ffn staging bugfix.
// - 1 node per block (48 edge rows), LDS 27136 B -> 6 blocks/CU (24 waves).
// - All conversions via v_cvt_pk_bf16_f32 (1 op / 2 floats).
// - gelu via raw v_exp/v_rcp builtins.
// - FFN fused into a single kernel (row-local), no xg round-trip.
// - k_edge MSG buffer stride 132 f32, 2 threads/row readback (conflict-free).
// LDS A-tile stride 264 shorts (132 dw = 4 mod 32 -> conflict-free b128 under
// 8-lane grouping); X1/X2 stride 136 shorts (68 dw = 4 mod 32, same property).

typedef __attribute__((ext_vector_type(8))) short short8;
typedef __attribute__((ext_vector_type(4))) float f32x4;

#define MFMA16(a,b,c) __builtin_amdgcn_mfma_f32_16x16x32_bf16((a),(b),(c),0,0,0)

#define L_SEQ 2048
#define K_NBR 48
#define H_DIM 128

__device__ __forceinline__ unsigned cvtpk(float lo, float hi){
  unsigned r;
  asm("v_cvt_pk_bf16_f32 %0, %1, %2" : "=v"(r) : "v"(lo), "v"(hi));
  return r;
}
__device__ __forceinline__ unsigned short f2bf(float x){ return (unsigned short)cvtpk(x, x); }
__device__ __forceinline__ float bflo(unsigned u){ return __uint_as_float(u << 16); }
__device__ __forceinline__ float bfhi(unsigned u){ return __uint_as_float(u & 0xffff0000u); }

// tanh-approx GELU via hw exp2 + hw rcp (max dev from erf-GELU ~3e-4)
__device__ __forceinline__ float gelu_f(float x){
  float t = fmaf(x * x, 0.044715f, 1.0f);
  float e = __builtin_amdgcn_exp2f(-2.3022082f * x * t);   // 2*sqrt(2/pi)*log2(e)
  return x * __builtin_amdgcn_rcpf(1.0f + e);
}

// ---------- K0a: Wt[c][r] = bf16(W[r][c]) ----------
__global__ void k_wt(const float* __restrict__ in, unsigned short* __restrict__ out,
                     int R, int C){
  int o = blockIdx.x * 256 + threadIdx.x;
  int c = o / R, r = o - c * R;
  out[o] = f2bf(in[r * C + c]);
}

// ---------- K0b: h_V -> bf16 ----------
__global__ void k_cvt16(const float* __restrict__ in, unsigned short* __restrict__ out){
  int i = blockIdx.x * 256 + threadIdx.x;       // float4 index
  float4 v = ((const float4*)in)[i];
  uint2 p;
  p.x = cvtpk(v.x, v.y);
  p.y = cvtpk(v.z, v.w);
  ((uint2*)out)[i] = p;
}

// ---------- K1: node message MLP + masked k-sum + LN1 ----------
__global__ __launch_bounds__(256, 6) void k_node(
  const float* __restrict__ hV, const float* __restrict__ hE,
  const unsigned short* __restrict__ hV16,
  const int* __restrict__ Eidx, const float* __restrict__ maskA,
  const unsigned short* __restrict__ Wt1, const float* __restrict__ b1,
  const unsigned short* __restrict__ Wt2, const float* __restrict__ b2,
  const unsigned short* __restrict__ Wt3, const float* __restrict__ b3,
  const float* __restrict__ n1g, const float* __restrict__ n1b,
  float* __restrict__ v32, unsigned short* __restrict__ v16)
{
  __shared__ __align__(16) short Abuf[13056];   // 26112 B: A(264) / X1+X2(136)
  __shared__ __align__(16) float aux[256];      // [0:128)=hv  [128:256)=sbias->dh

  const int tid  = threadIdx.x;
  const int node = blockIdx.x;
  const int b    = node >> 11;

  if (tid < 128) aux[tid] = hV[(size_t)node * H_DIM + tid];

  // stage A: cols 0..127 = h_E (cvt_pk), 128..255 = gathered h_V (bf16 copy)
  const float4* srcE = (const float4*)(hE + (size_t)node * K_NBR * H_DIM);
  #pragma unroll
  for (int ii = 0; ii < 6; ++ii) {
    int i = tid + ii * 256;
    float4 v = srcE[i];
    int r = i >> 5, c = (i & 31) << 2;
    uint2 p; p.x = cvtpk(v.x, v.y); p.y = cvtpk(v.z, v.w);
    *(uint2*)&Abuf[r * 264 + c] = p;
  }
  const int* eip = Eidx + (size_t)node * K_NBR;
  #pragma unroll
  for (int ii = 0; ii < 6; ++ii) {
    int i = tid + ii * 256;
    int r = i >> 5, c = i & 31;
    int e = eip[r];
    *(uint2*)&Abuf[r * 264 + 128 + (c << 2)] =
        ((const uint2*)(hV16 + ((size_t)(b * L_SEQ) + e) * H_DIM))[c];
  }
  __syncthreads();

  // sbias[c] = b1[c] + h_V_self . W1[0:128][c]
  if (tid < 128) {
    float acc = b1[tid];
    const unsigned* w = (const unsigned*)(Wt1 + (size_t)tid * 384);
    const float4* h4 = (const float4*)aux;
    #pragma unroll 8
    for (int j = 0; j < 32; ++j) {
      float4 hh = h4[j];
      unsigned w0 = w[2 * j], w1 = w[2 * j + 1];
      acc = fmaf(hh.x, bflo(w0), acc);
      acc = fmaf(hh.y, bfhi(w0), acc);
      acc = fmaf(hh.z, bflo(w1), acc);
      acc = fmaf(hh.w, bfhi(w1), acc);
    }
    aux[128 + tid] = acc;
  }

  const int wid = tid >> 6, lane = tid & 63;
  const int lr = lane & 15, lg = lane >> 4, kele = lg * 8;

  f32x4 zero = {0.f, 0.f, 0.f, 0.f};
  f32x4 acc[3][2];
  #pragma unroll
  for (int t = 0; t < 3; ++t)
    #pragma unroll
    for (int n = 0; n < 2; ++n) acc[t][n] = zero;

  // ---- layer 1 (K=256, edge+neighbor thirds)
  #pragma unroll 2
  for (int kk = 0; kk < 8; ++kk) {
    short8 a0 = *(const short8*)&Abuf[(lr     ) * 264 + kk * 32 + kele];
    short8 a1 = *(const short8*)&Abuf[(lr + 16) * 264 + kk * 32 + kele];
    short8 a2 = *(const short8*)&Abuf[(lr + 32) * 264 + kk * 32 + kele];
    #pragma unroll
    for (int n = 0; n < 2; ++n) {
      short8 bf = *(const short8*)(const void*)(Wt1 + (size_t)(wid * 32 + n * 16 + lr) * 384 + 128 + kk * 32 + kele);
      acc[0][n] = MFMA16(a0, bf, acc[0][n]);
      acc[1][n] = MFMA16(a1, bf, acc[1][n]);
      acc[2][n] = MFMA16(a2, bf, acc[2][n]);
    }
  }
  __syncthreads();                       // A reads done -> region becomes X1/X2
  #pragma unroll
  for (int t = 0; t < 3; ++t)
    #pragma unroll
    for (int n = 0; n < 2; ++n) {
      int col = wid * 32 + n * 16 + lr;
      float sb = aux[128 + col];
      #pragma unroll
      for (int r = 0; r < 4; ++r) {
        int row = t * 16 + lg * 4 + r;
        Abuf[row * 136 + col] = (short)cvtpk(gelu_f(acc[t][n][r] + sb), 0.f);
      }
    }
  __syncthreads();                       // X1 ready

  // ---- layer 2 (K=128)
  #pragma unroll
  for (int t = 0; t < 3; ++t)
    #pragma unroll
    for (int n = 0; n < 2; ++n) acc[t][n] = zero;
  #pragma unroll
  for (int kk = 0; kk < 4; ++kk) {
    short8 a0 = *(const short8*)&Abuf[(lr     ) * 136 + kk * 32 + kele];
    short8 a1 = *(const short8*)&Abuf[(lr + 16) * 136 + kk * 32 + kele];
    short8 a2 = *(const short8*)&Abuf[(lr + 32) * 136 + kk * 32 + kele];
    #pragma unroll
    for (int n = 0; n < 2; ++n) {
      short8 bf = *(const short8*)(const void*)(Wt2 + (size_t)(wid * 32 + n * 16 + lr) * 128 + kk * 32 + kele);
      acc[0][n] = MFMA16(a0, bf, acc[0][n]);
      acc[1][n] = MFMA16(a1, bf, acc[1][n]);
      acc[2][n] = MFMA16(a2, bf, acc[2][n]);
    }
  }
  #pragma unroll
  for (int t = 0; t < 3; ++t)            // X2 at +6528 shorts
    #pragma unroll
    for (int n = 0; n < 2; ++n) {
      int col = wid * 32 + n * 16 + lr;
      float bb = b2[col];
      #pragma unroll
      for (int r = 0; r < 4; ++r) {
        int row = t * 16 + lg * 4 + r;
        Abuf[6528 + row * 136 + col] = (short)cvtpk(gelu_f(acc[t][n][r] + bb), 0.f);
      }
    }
  __syncthreads();                       // X2 ready

  // ---- layer 3 (K=128) + mask + k-sum
  #pragma unroll
  for (int t = 0; t < 3; ++t)
    #pragma unroll
    for (int n = 0; n < 2; ++n) acc[t][n] = zero;
  #pragma unroll
  for (int kk = 0; kk < 4; ++kk) {
    short8 a0 = *(const short8*)&Abuf[6528 + (lr     ) * 136 + kk * 32 + kele];
    short8 a1 = *(const short8*)&Abuf[6528 + (lr + 16) * 136 + kk * 32 + kele];
    short8 a2 = *(const short8*)&Abuf[6528 + (lr + 32) * 136 + kk * 32 + kele];
    #pragma unroll
    for (int n = 0; n < 2; ++n) {
      short8 bf = *(const short8*)(const void*)(Wt3 + (size_t)(wid * 32 + n * 16 + lr) * 128 + kk * 32 + kele);
      acc[0][n] = MFMA16(a0, bf, acc[0][n]);
      acc[1][n] = MFMA16(a1, bf, acc[1][n]);
      acc[2][n] = MFMA16(a2, bf, acc[2][n]);
    }
  }
  const float* mrow = maskA + (size_t)node * K_NBR;
  float mk[3][4];
  #pragma unroll
  for (int t = 0; t < 3; ++t)
    #pragma unroll
    for (int r = 0; r < 4; ++r) mk[t][r] = mrow[t * 16 + lg * 4 + r];
  float part[2];
  #pragma unroll
  for (int n = 0; n < 2; ++n) {
    int col = wid * 32 + n * 16 + lr;
    float bb = b3[col];
    float p = 0.f;
    #pragma unroll
    for (int t = 0; t < 3; ++t)
      #pragma unroll
      for (int r = 0; r < 4; ++r)
        p += (acc[t][n][r] + bb) * mk[t][r];
    part[n] = p;
  }
  #pragma unroll
  for (int n = 0; n < 2; ++n) {
    part[n] += __shfl_xor(part[n], 16);
    part[n] += __shfl_xor(part[n], 32);
  }
  if (lane < 16) {
    #pragma unroll
    for (int n = 0; n < 2; ++n)
      aux[128 + wid * 32 + n * 16 + lane] = part[n] * (1.f / 30.f);
  }
  __syncthreads();

  // ---- LN1 -> v (fp32 + bf16), wave 0
  if (wid == 0) {
    float u0 = aux[lane]      + aux[128 + lane];
    float u1 = aux[lane + 64] + aux[192 + lane];
    float s1 = u0 + u1, s2 = u0 * u0 + u1 * u1;
    #pragma unroll
    for (int off = 1; off < 64; off <<= 1) {
      s1 += __shfl_xor(s1, off);
      s2 += __shfl_xor(s2, off);
    }
    float mean = s1 * 0.0078125f;
    float var  = fmaf(s2, 0.0078125f, -mean * mean);
    float rs = rsqrtf(var + 1e-5f);
    float vv0 = (u0 - mean) * rs * n1g[lane]      + n1b[lane];
    float vv1 = (u1 - mean) * rs * n1g[lane + 64] + n1b[lane + 64];
    v32[(size_t)node * 128 + lane]      = vv0;
    v32[(size_t)node * 128 + lane + 64] = vv1;
    v16[(size_t)node * 128 + lane]      = f2bf(vv0);
    v16[(size_t)node * 128 + lane + 64] = f2bf(vv1);
  }
}

// ---------- K2: fused FFN: h_Vnew = mask_V * LN2(v + gelu(v@Wgi+bgi)@Wgo+bgo)
__global__ __launch_bounds__(256, 4) void k_ffn(
  const unsigned short* __restrict__ v16,
  const unsigned short* __restrict__ Wtgi, const float* __restrict__ bgi,
  const unsigned short* __restrict__ Wtgo, const float* __restrict__ bgo,
  const float* __restrict__ v32,
  const float* __restrict__ n2g, const float* __restrict__ n2b,
  const float* __restrict__ maskV, float* __restrict__ outV)
{
  __shared__ __align__(16) short Av[2176];    // 16 x 136
  __shared__ __align__(16) short Xb[8320];    // 16 x 520; overlaid by U (16x132 f32)
  float* U = (float*)Xb;
  const int tid = threadIdx.x;
  const int row0 = blockIdx.x * 16;
  // 16 rows x 128 cols bf16 = 512 uint2  (R2 bug: loaded only 256, wrong map)
  const uint2* src = (const uint2*)(v16 + (size_t)row0 * H_DIM);
  for (int i = tid; i < 512; i += 256) {
    int r = i >> 5, c = (i & 31) << 2;
    *(uint2*)&Av[r * 136 + c] = src[i];
  }
  __syncthreads();
  const int wid = tid >> 6, lane = tid & 63;
  const int lr = lane & 15, lg = lane >> 4, kele = lg * 8;
  f32x4 zero = {0.f, 0.f, 0.f, 0.f};
  f32x4 acc[8];
  #pragma unroll
  for (int n = 0; n < 8; ++n) acc[n] = zero;
  #pragma unroll
  for (int kk = 0; kk < 4; ++kk) {
    short8 a = *(const short8*)&Av[lr * 136 + kk * 32 + kele];
    #pragma unroll
    for (int n = 0; n < 8; ++n) {
      short8 bf = *(const short8*)(const void*)(Wtgi + (size_t)(wid * 128 + n * 16 + lr) * 128 + kk * 32 + kele);
      acc[n] = MFMA16(a, bf, acc[n]);
    }
  }
  #pragma unroll
  for (int n = 0; n < 8; ++n) {
    int col = wid * 128 + n * 16 + lr;
    float bb = bgi[col];
    #pragma unroll
    for (int r = 0; r < 4; ++r) {
      int row = lg * 4 + r;
      Xb[row * 520 + col] = (short)cvtpk(gelu_f(acc[n][r] + bb), 0.f);
    }
  }
  __syncthreads();
  f32x4 acc2[2];
  #pragma unroll
  for (int n = 0; n < 2; ++n) acc2[n] = zero;
  #pragma unroll 4
  for (int kk = 0; kk < 16; ++kk) {
    short8 a = *(const short8*)&Xb[lr * 520 + kk * 32 + kele];
    #pragma unroll
    for (int n = 0; n < 2; ++n) {
      short8 bf = *(const short8*)(const void*)(Wtgo + (size_t)(wid * 32 + n * 16 + lr) * 512 + kk * 32 + kele);
      acc2[n] = MFMA16(a, bf, acc2[n]);
    }
  }
  __syncthreads();                  // all Xb reads done before U overlay
  #pragma unroll
  for (int n = 0; n < 2; ++n) {
    int col = wid * 32 + n * 16 + lr;
    float bb = bgo[col];
    #pragma unroll
    for (int r = 0; r < 4; ++r) {
      int row = lg * 4 + r;
      U[row * 132 + col] = acc2[n][r] + bb + v32[(size_t)(row0 + row) * 128 + col];
    }
  }
  __syncthreads();
  if (tid < 128) {
    int r = tid >> 3, sub = tid & 7;
    const float* Ur = &U[r * 132 + sub * 16];
    float u[16]; float s1 = 0.f, s2 = 0.f;
    #pragma unroll
    for (int i = 0; i < 16; ++i) { u[i] = Ur[i]; s1 += u[i]; s2 += u[i] * u[i]; }
    s1 += __shfl_xor(s1, 1); s1 += __shfl_xor(s1, 2); s1 += __shfl_xor(s1, 4);
    s2 += __shfl_xor(s2, 1); s2 += __shfl_xor(s2, 2); s2 += __shfl_xor(s2, 4);
    float mean = s1 * 0.0078125f;
    float var  = fmaf(s2, 0.0078125f, -mean * mean);
    float rs = rsqrtf(var + 1e-5f);
    int nd = row0 + r;
    float mv = maskV[nd];
    float* dst = outV + (size_t)nd * 128 + sub * 16;
    #pragma unroll
    for (int i = 0; i < 16; ++i) {
      int c = sub * 16 + i;
      dst[i] = ((u[i] - mean) * rs * n2g[c] + n2b[c]) * mv;
    }
  }
}

// ---------- K3: edge message MLP + residual + LN3 ----------
__global__ __launch_bounds__(256, 6) void k_edge(
  const float* __restrict__ hE, const int* __restrict__ Eidx,
  const float* __restrict__ hVn,
  const unsigned short* __restrict__ Wt11, const float* __restrict__ b11,
  const unsigned short* __restrict__ Wt12, const float* __restrict__ b12,
  const unsigned short* __restrict__ Wt13, const float* __restrict__ b13,
  const float* __restrict__ n3g, const float* __restrict__ n3b,
  float* __restrict__ outE)
{
  __shared__ __align__(16) short Abuf[13056];
  __shared__ __align__(16) float aux[256];   // hv+sbias, later gamma|beta
  float* MSG = (float*)Abuf;                 // stride 132 floats (layer-3 out)

  const int tid  = threadIdx.x;
  const int node = blockIdx.x;
  const int b    = node >> 11;

  if (tid < 128) aux[tid] = hVn[(size_t)node * H_DIM + tid];

  const float4* srcE = (const float4*)(hE + (size_t)node * K_NBR * H_DIM);
  #pragma unroll
  for (int ii = 0; ii < 6; ++ii) {
    int i = tid + ii * 256;
    float4 v = srcE[i];
    int r = i >> 5, c = (i & 31) << 2;
    uint2 p; p.x = cvtpk(v.x, v.y); p.y = cvtpk(v.z, v.w);
    *(uint2*)&Abuf[r * 264 + c] = p;
  }
  const int* eip = Eidx + (size_t)node * K_NBR;
  #pragma unroll
  for (int ii = 0; ii < 6; ++ii) {
    int i = tid + ii * 256;
    int r = i >> 5, c = i & 31;
    int e = eip[r];
    float4 v = ((const float4*)(hVn + ((size_t)(b * L_SEQ) + e) * H_DIM))[c];
    uint2 p; p.x = cvtpk(v.x, v.y); p.y = cvtpk(v.z, v.w);
    *(uint2*)&Abuf[r * 264 + 128 + (c << 2)] = p;
  }
  __syncthreads();

  if (tid < 128) {
    float acc = b11[tid];
    const unsigned* w = (const unsigned*)(Wt11 + (size_t)tid * 384);
    const float4* h4 = (const float4*)aux;
    #pragma unroll 8
    for (int j = 0; j < 32; ++j) {
      float4 hh = h4[j];
      unsigned w0 = w[2 * j], w1 = w[2 * j + 1];
      acc = fmaf(hh.x, bflo(w0), acc);
      acc = fmaf(hh.y, bfhi(w0), acc);
      acc = fmaf(hh.z, bflo(w1), acc);
      acc = fmaf(hh.w, bfhi(w1), acc);
    }
    aux[128 + tid] = acc;
  }

  const int wid = tid >> 6, lane = tid & 63;
  const int lr = lane & 15, lg = lane >> 4, kele = lg * 8;

  f32x4 zero = {0.f, 0.f, 0.f, 0.f};
  f32x4 acc[3][2];
  #pragma unroll
  for (int t = 0; t < 3; ++t)
    #pragma unroll
    for (int n = 0; n < 2; ++n) acc[t][n] = zero;

  #pragma unroll 2
  for (int kk = 0; kk < 8; ++kk) {
    short8 a0 = *(const short8*)&Abuf[(lr     ) * 264 + kk * 32 + kele];
    short8 a1 = *(const short8*)&Abuf[(lr + 16) * 264 + kk * 32 + kele];
    short8 a2 = *(const short8*)&Abuf[(lr + 32) * 264 + kk * 32 + kele];
    #pragma unroll
    for (int n = 0; n < 2; ++n) {
      short8 bf = *(const short8*)(const void*)(Wt11 + (size_t)(wid * 32 + n * 16 + lr) * 384 + 128 + kk * 32 + kele);
      acc[0][n] = MFMA16(a0, bf, acc[0][n]);
      acc[1][n] = MFMA16(a1, bf, acc[1][n]);
      acc[2][n] = MFMA16(a2, bf, acc[2][n]);
    }
  }
  __syncthreads();
  #pragma unroll
  for (int t = 0; t < 3; ++t)
    #pragma unroll
    for (int n = 0; n < 2; ++n) {
      int col = wid * 32 + n * 16 + lr;
      float sb = aux[128 + col];
      #pragma unroll
      for (int r = 0; r < 4; ++r) {
        int row = t * 16 + lg * 4 + r;
        Abuf[row * 136 + col] = (short)cvtpk(gelu_f(acc[t][n][r] + sb), 0.f);
      }
    }
  __syncthreads();                 // X1 ready; hv+sbias dead -> stage gamma|beta
  if (tid < 128) {
    aux[tid]       = n3g[tid];
    aux[128 + tid] = n3b[tid];
  }

  #pragma unroll
  for (int t = 0; t < 3; ++t)
    #pragma unroll
    for (int n = 0; n < 2; ++n) acc[t][n] = zero;
  #pragma unroll
  for (int kk = 0; kk < 4; ++kk) {
    short8 a0 = *(const short8*)&Abuf[(lr     ) * 136 + kk * 32 + kele];
    short8 a1 = *(const short8*)&Abuf[(lr + 16) * 136 + kk * 32 + kele];
    short8 a2 = *(const short8*)&Abuf[(lr + 32) * 136 + kk * 32 + kele];
    #pragma unroll
    for (int n = 0; n < 2; ++n) {
      short8 bf = *(const short8*)(const void*)(Wt12 + (size_t)(wid * 32 + n * 16 + lr) * 128 + kk * 32 + kele);
      acc[0][n] = MFMA16(a0, bf, acc[0][n]);
      acc[1][n] = MFMA16(a1, bf, acc[1][n]);
      acc[2][n] = MFMA16(a2, bf, acc[2][n]);
    }
  }
  #pragma unroll
  for (int t = 0; t < 3; ++t)
    #pragma unroll
    for (int n = 0; n < 2; ++n) {
      int col = wid * 32 + n * 16 + lr;
      float bb = b12[col];
      #pragma unroll
      for (int r = 0; r < 4; ++r) {
        int row = t * 16 + lg * 4 + r;
        Abuf[6528 + row * 136 + col] = (short)cvtpk(gelu_f(acc[t][n][r] + bb), 0.f);
      }
    }
  __syncthreads();

  #pragma unroll
  for (int t = 0; t < 3; ++t)
    #pragma unroll
    for (int n = 0; n < 2; ++n) acc[t][n] = zero;
  #pragma unroll
  for (int kk = 0; kk < 4; ++kk) {
    short8 a0 = *(const short8*)&Abuf[6528 + (lr     ) * 136 + kk * 32 + kele];
    short8 a1 = *(const short8*)&Abuf[6528 + (lr + 16) * 136 + kk * 32 + kele];
    short8 a2 = *(const short8*)&Abuf[6528 + (lr + 32) * 136 + kk * 32 + kele];
    #pragma unroll
    for (int n = 0; n < 2; ++n) {
      short8 bf = *(const short8*)(const void*)(Wt13 + (size_t)(wid * 32 + n * 16 + lr) * 128 + kk * 32 + kele);
      acc[0][n] = MFMA16(a0, bf, acc[0][n]);
      acc[1][n] = MFMA16(a1, bf, acc[1][n]);
      acc[2][n] = MFMA16(a2, bf, acc[2][n]);
    }
  }
  __syncthreads();                       // X2 reads done; region becomes MSG
  #pragma unroll
  for (int t = 0; t < 3; ++t)
    #pragma unroll
    for (int n = 0; n < 2; ++n) {
      int col = wid * 32 + n * 16 + lr;
      float bb = b13[col];
      #pragma unroll
      for (int r = 0; r < 4; ++r) {
        int row = t * 16 + lg * 4 + r;
        MSG[row * 132 + col] = acc[t][n][r] + bb;
      }
    }
  __syncthreads();

  // per-edge residual + LN3: 2 threads per edge row
  if (tid < 96) {
    int rr = tid >> 1, half = tid & 1;
    size_t ebase = ((size_t)node * K_NBR + rr) * H_DIM;
    const float4* he4 = (const float4*)(hE + ebase) + half * 16;
    const float4* m4  = (const float4*)(MSG + rr * 132) + half * 16;
    float s1 = 0.f, s2 = 0.f;
    #pragma unroll 4
    for (int i = 0; i < 16; ++i) {
      float4 a = he4[i]; float4 mm = m4[i];
      float x0 = a.x + mm.x, x1 = a.y + mm.y, x2 = a.z + mm.z, x3 = a.w + mm.w;
      s1 += x0 + x1 + x2 + x3;
      s2 += x0 * x0 + x1 * x1 + x2 * x2 + x3 * x3;
    }
    s1 += __shfl_xor(s1, 1);
    s2 += __shfl_xor(s2, 1);
    float mean = s1 * 0.0078125f;
    float var  = fmaf(s2, 0.0078125f, -mean * mean);
    float rs = rsqrtf(var + 1e-5f);
    float4* dst = (float4*)(outE + ebase) + half * 16;
    #pragma unroll 4
    for (int i = 0; i < 16; ++i) {
      float4 a = he4[i]; float4 mm = m4[i];
      int c = half * 64 + i * 4;
      float4 o;
      o.x = (a.x + mm.x - mean) * rs * aux[c + 0] + aux[128 + c + 0];
      o.y = (a.y + mm.y - mean) * rs * aux[c + 1] + aux[128 + c + 1];
      o.z = (a.z + mm.z - mean) * rs * aux[c + 2] + aux[128 + c + 2];
      o.w = (a.w + mm.w - mean) * rs * aux[c + 3] + aux[128 + c + 3];
      dst[i] = o;
    }
  }
}

extern "C" void kernel_launch(void* const* d_in, const int* in_sizes, int n_in,
                              void* d_out, int out_size, void* d_ws, size_t ws_size,
                              hipStream_t stream) {
  const float* hV   = (const float*)d_in[0];
  const float* hE   = (const float*)d_in[1];
  const int*   Eidx = (const int*)d_in[2];
  const float* maskV= (const float*)d_in[3];
  const float* maskA= (const float*)d_in[4];
  const float* W1 = (const float*)d_in[5];  const float* b1 = (const float*)d_in[6];
  const float* W2 = (const float*)d_in[7];  const float* b2 = (const float*)d_in[8];
  const float* W3 = (const float*)d_in[9];  const float* b3 = (const float*)d_in[10];
  const float* W11= (const float*)d_in[11]; const float* b11= (const float*)d_in[12];
  const float* W12= (const float*)d_in[13]; const float* b12= (const float*)d_in[14];
  const float* W13= (const float*)d_in[15]; const float* b13= (const float*)d_in[16];
  const float* Wgi= (const float*)d_in[17]; const float* bgi= (const float*)d_in[18];
  const float* Wgo= (const float*)d_in[19]; const float* bgo= (const float*)d_in[20];
  const float* n1g= (const float*)d_in[21]; const float* n1b= (const float*)d_in[22];
  const float* n2g= (const float*)d_in[23]; const float* n2b= (const float*)d_in[24];
  const float* n3g= (const float*)d_in[25]; const float* n3b= (const float*)d_in[26];

  float* outV = (float*)d_out;
  float* outE = outV + (size_t)4 * 2048 * 128;   // h_E output region

  // d_ws: transposed bf16 weights only (~590 KB) — read during k_edge, so
  // must be outside the h_E output region.
  unsigned short* wsu  = (unsigned short*)d_ws;
  unsigned short* Wt1  = wsu + 0;
  unsigned short* Wt2  = wsu + 49152;
  unsigned short* Wt3  = wsu + 65536;
  unsigned short* Wt11 = wsu + 81920;
  unsigned short* Wt12 = wsu + 131072;
  unsigned short* Wt13 = wsu + 147456;
  unsigned short* Wtgi = wsu + 163840;
  unsigned short* Wtgo = wsu + 229376;

  // large intermediates live in the not-yet-written h_E output region
  // (all dead before k_edge starts writing it)
  char* scr = (char*)outE;
  unsigned short* hV16 = (unsigned short*)scr;                     // 2 MB
  float*          v32  = (float*)(scr + (size_t)2097152);          // 4 MB
  unsigned short* v16  = (unsigned short*)(scr + (size_t)6291456); // 2 MB

  k_wt<<<192, 256, 0, stream>>>(W1,  Wt1,  384, 128);
  k_wt<<<64,  256, 0, stream>>>(W2,  Wt2,  128, 128);
  k_wt<<<64,  256, 0, stream>>>(W3,  Wt3,  128, 128);
  k_wt<<<192, 256, 0, stream>>>(W11, Wt11, 384, 128);
  k_wt<<<64,  256, 0, stream>>>(W12, Wt12, 128, 128);
  k_wt<<<64,  256, 0, stream>>>(W13, Wt13, 128, 128);
  k_wt<<<256, 256, 0, stream>>>(Wgi, Wtgi, 128, 512);
  k_wt<<<256, 256, 0, stream>>>(Wgo, Wtgo, 512, 128);
  k_cvt16<<<1024, 256, 0, stream>>>(hV, hV16);

  k_node<<<8192, 256, 0, stream>>>(hV, hE, hV16, Eidx, maskA,
                                   Wt1, b1, Wt2, b2, Wt3, b3, n1g, n1b, v32, v16);
  k_ffn<<<512, 256, 0, stream>>>(v16, Wtgi, bgi, Wtgo, bgo, v32,
                                 n2g, n2b, maskV, outV);
  k_edge<<<8192, 256, 0, stream>>>(hE, Eidx, outV,
                                   Wt11, b11, Wt12, b12, Wt13, b13, n3g, n3b, outE);
}

// Round 4
// 783.164 us; speedup vs baseline: 1.2664x; 1.0554x over previous
//
#include <hip/hip_runtime.h>

// ProteinMPNN encoder layer, MI355X/gfx950.  R4: un-choke VGPRs + K=384 fold.
// - launch_bounds(256,4): VGPR cap 128 (R3's cap of 40 serialized all loads).
// - Self-h_V third folded into MFMA as 4 broadcast K-tiles (K=384 layer 1);
//   removes the serial per-thread sbias dot-product phase.
// - 1 node per block (48 edge rows); LDS ~27KB.
// - LN3 readback widened to 192 threads (4 per edge row).
// LDS A-tile stride 264 shorts, X1/X2 stride 136 shorts (both balanced for
// b128 reads: 256 dwords spread 8/bank).

typedef __attribute__((ext_vector_type(8))) short short8;
typedef __attribute__((ext_vector_type(4))) float f32x4;

#define MFMA16(a,b,c) __builtin_amdgcn_mfma_f32_16x16x32_bf16((a),(b),(c),0,0,0)

#define L_SEQ 2048
#define K_NBR 48
#define H_DIM 128

__device__ __forceinline__ unsigned cvtpk(float lo, float hi){
  unsigned r;
  asm("v_cvt_pk_bf16_f32 %0, %1, %2" : "=v"(r) : "v"(lo), "v"(hi));
  return r;
}
__device__ __forceinline__ unsigned short f2bf(float x){ return (unsigned short)cvtpk(x, x); }

// tanh-approx GELU via hw exp2 + hw rcp (max dev from erf-GELU ~3e-4)
__device__ __forceinline__ float gelu_f(float x){
  float t = fmaf(x * x, 0.044715f, 1.0f);
  float e = __builtin_amdgcn_exp2f(-2.3022082f * x * t);   // 2*sqrt(2/pi)*log2(e)
  return x * __builtin_amdgcn_rcpf(1.0f + e);
}

// ---------- K0a: Wt[c][r] = bf16(W[r][c]) ----------
__global__ void k_wt(const float* __restrict__ in, unsigned short* __restrict__ out,
                     int R, int C){
  int o = blockIdx.x * 256 + threadIdx.x;
  int c = o / R, r = o - c * R;
  out[o] = f2bf(in[r * C + c]);
}

// ---------- K0b: h_V -> bf16 ----------
__global__ void k_cvt16(const float* __restrict__ in, unsigned short* __restrict__ out){
  int i = blockIdx.x * 256 + threadIdx.x;       // float4 index
  float4 v = ((const float4*)in)[i];
  uint2 p;
  p.x = cvtpk(v.x, v.y);
  p.y = cvtpk(v.z, v.w);
  ((uint2*)out)[i] = p;
}

// ---------- K1: node message MLP + masked k-sum + LN1 ----------
__global__ __launch_bounds__(256, 4) void k_node(
  const float* __restrict__ hV, const float* __restrict__ hE,
  const unsigned short* __restrict__ hV16,
  const int* __restrict__ Eidx, const float* __restrict__ maskA,
  const unsigned short* __restrict__ Wt1, const float* __restrict__ b1,
  const unsigned short* __restrict__ Wt2, const float* __restrict__ b2,
  const unsigned short* __restrict__ Wt3, const float* __restrict__ b3,
  const float* __restrict__ n1g, const float* __restrict__ n1b,
  float* __restrict__ v32, unsigned short* __restrict__ v16)
{
  __shared__ __align__(16) short Abuf[13056];   // A: 48x264 / X1+X2: 2x48x136
  __shared__ __align__(16) short hvs[128];      // self h_V, bf16 (broadcast rows)
  __shared__ __align__(16) float aux[256];      // [0:128)=hv f32, [128:256)=dh

  const int tid  = threadIdx.x;
  const int node = blockIdx.x;
  const int b    = node >> 11;

  if (tid < 128) aux[tid] = hV[(size_t)node * H_DIM + tid];
  if (tid < 32)
    ((uint2*)hvs)[tid] = ((const uint2*)(hV16 + (size_t)node * H_DIM))[tid];

  // stage A: cols 0..127 = h_E (cvt_pk), 128..255 = gathered h_V (bf16 copy)
  const float4* srcE = (const float4*)(hE + (size_t)node * K_NBR * H_DIM);
  #pragma unroll
  for (int ii = 0; ii < 6; ++ii) {
    int i = tid + ii * 256;
    float4 v = srcE[i];
    int r = i >> 5, c = (i & 31) << 2;
    uint2 p; p.x = cvtpk(v.x, v.y); p.y = cvtpk(v.z, v.w);
    *(uint2*)&Abuf[r * 264 + c] = p;
  }
  const int* eip = Eidx + (size_t)node * K_NBR;
  #pragma unroll
  for (int ii = 0; ii < 6; ++ii) {
    int i = tid + ii * 256;
    int r = i >> 5, c = i & 31;
    int e = eip[r];
    *(uint2*)&Abuf[r * 264 + 128 + (c << 2)] =
        ((const uint2*)(hV16 + ((size_t)(b * L_SEQ) + e) * H_DIM))[c];
  }
  __syncthreads();

  const int wid = tid >> 6, lane = tid & 63;
  const int lr = lane & 15, lg = lane >> 4, kele = lg * 8;

  f32x4 zero = {0.f, 0.f, 0.f, 0.f};
  f32x4 acc[3][2];
  #pragma unroll
  for (int t = 0; t < 3; ++t)
    #pragma unroll
    for (int n = 0; n < 2; ++n) acc[t][n] = zero;

  // ---- layer 1, K=384: 4 broadcast self-kk + 8 staged kk
  #pragma unroll
  for (int kk = 0; kk < 4; ++kk) {
    short8 as = *(const short8*)&hvs[kk * 32 + kele];
    #pragma unroll
    for (int n = 0; n < 2; ++n) {
      short8 bf = *(const short8*)(const void*)(Wt1 + (size_t)(wid * 32 + n * 16 + lr) * 384 + kk * 32 + kele);
      acc[0][n] = MFMA16(as, bf, acc[0][n]);
      acc[1][n] = MFMA16(as, bf, acc[1][n]);
      acc[2][n] = MFMA16(as, bf, acc[2][n]);
    }
  }
  #pragma unroll 2
  for (int kk = 0; kk < 8; ++kk) {
    short8 a0 = *(const short8*)&Abuf[(lr     ) * 264 + kk * 32 + kele];
    short8 a1 = *(const short8*)&Abuf[(lr + 16) * 264 + kk * 32 + kele];
    short8 a2 = *(const short8*)&Abuf[(lr + 32) * 264 + kk * 32 + kele];
    #pragma unroll
    for (int n = 0; n < 2; ++n) {
      short8 bf = *(const short8*)(const void*)(Wt1 + (size_t)(wid * 32 + n * 16 + lr) * 384 + 128 + kk * 32 + kele);
      acc[0][n] = MFMA16(a0, bf, acc[0][n]);
      acc[1][n] = MFMA16(a1, bf, acc[1][n]);
      acc[2][n] = MFMA16(a2, bf, acc[2][n]);
    }
  }
  __syncthreads();                       // A reads done -> region becomes X1/X2
  #pragma unroll
  for (int t = 0; t < 3; ++t)
    #pragma unroll
    for (int n = 0; n < 2; ++n) {
      int col = wid * 32 + n * 16 + lr;
      float bb = b1[col];
      #pragma unroll
      for (int r = 0; r < 4; ++r) {
        int row = t * 16 + lg * 4 + r;
        Abuf[row * 136 + col] = (short)cvtpk(gelu_f(acc[t][n][r] + bb), 0.f);
      }
    }
  __syncthreads();                       // X1 ready

  // ---- layer 2 (K=128)
  #pragma unroll
  for (int t = 0; t < 3; ++t)
    #pragma unroll
    for (int n = 0; n < 2; ++n) acc[t][n] = zero;
  #pragma unroll
  for (int kk = 0; kk < 4; ++kk) {
    short8 a0 = *(const short8*)&Abuf[(lr     ) * 136 + kk * 32 + kele];
    short8 a1 = *(const short8*)&Abuf[(lr + 16) * 136 + kk * 32 + kele];
    short8 a2 = *(const short8*)&Abuf[(lr + 32) * 136 + kk * 32 + kele];
    #pragma unroll
    for (int n = 0; n < 2; ++n) {
      short8 bf = *(const short8*)(const void*)(Wt2 + (size_t)(wid * 32 + n * 16 + lr) * 128 + kk * 32 + kele);
      acc[0][n] = MFMA16(a0, bf, acc[0][n]);
      acc[1][n] = MFMA16(a1, bf, acc[1][n]);
      acc[2][n] = MFMA16(a2, bf, acc[2][n]);
    }
  }
  #pragma unroll
  for (int t = 0; t < 3; ++t)            // X2 at +6528 shorts
    #pragma unroll
    for (int n = 0; n < 2; ++n) {
      int col = wid * 32 + n * 16 + lr;
      float bb = b2[col];
      #pragma unroll
      for (int r = 0; r < 4; ++r) {
        int row = t * 16 + lg * 4 + r;
        Abuf[6528 + row * 136 + col] = (short)cvtpk(gelu_f(acc[t][n][r] + bb), 0.f);
      }
    }
  __syncthreads();                       // X2 ready

  // ---- layer 3 (K=128) + mask + k-sum
  #pragma unroll
  for (int t = 0; t < 3; ++t)
    #pragma unroll
    for (int n = 0; n < 2; ++n) acc[t][n] = zero;
  #pragma unroll
  for (int kk = 0; kk < 4; ++kk) {
    short8 a0 = *(const short8*)&Abuf[6528 + (lr     ) * 136 + kk * 32 + kele];
    short8 a1 = *(const short8*)&Abuf[6528 + (lr + 16) * 136 + kk * 32 + kele];
    short8 a2 = *(const short8*)&Abuf[6528 + (lr + 32) * 136 + kk * 32 + kele];
    #pragma unroll
    for (int n = 0; n < 2; ++n) {
      short8 bf = *(const short8*)(const void*)(Wt3 + (size_t)(wid * 32 + n * 16 + lr) * 128 + kk * 32 + kele);
      acc[0][n] = MFMA16(a0, bf, acc[0][n]);
      acc[1][n] = MFMA16(a1, bf, acc[1][n]);
      acc[2][n] = MFMA16(a2, bf, acc[2][n]);
    }
  }
  const float* mrow = maskA + (size_t)node * K_NBR;
  float mk[3][4];
  #pragma unroll
  for (int t = 0; t < 3; ++t)
    #pragma unroll
    for (int r = 0; r < 4; ++r) mk[t][r] = mrow[t * 16 + lg * 4 + r];
  float part[2];
  #pragma unroll
  for (int n = 0; n < 2; ++n) {
    int col = wid * 32 + n * 16 + lr;
    float bb = b3[col];
    float p = 0.f;
    #pragma unroll
    for (int t = 0; t < 3; ++t)
      #pragma unroll
      for (int r = 0; r < 4; ++r)
        p += (acc[t][n][r] + bb) * mk[t][r];
    part[n] = p;
  }
  #pragma unroll
  for (int n = 0; n < 2; ++n) {
    part[n] += __shfl_xor(part[n], 16);
    part[n] += __shfl_xor(part[n], 32);
  }
  if (lane < 16) {
    #pragma unroll
    for (int n = 0; n < 2; ++n)
      aux[128 + wid * 32 + n * 16 + lane] = part[n] * (1.f / 30.f);
  }
  __syncthreads();

  // ---- LN1 -> v (fp32 + bf16), wave 0
  if (wid == 0) {
    float u0 = aux[lane]      + aux[128 + lane];
    float u1 = aux[lane + 64] + aux[192 + lane];
    float s1 = u0 + u1, s2 = u0 * u0 + u1 * u1;
    #pragma unroll
    for (int off = 1; off < 64; off <<= 1) {
      s1 += __shfl_xor(s1, off);
      s2 += __shfl_xor(s2, off);
    }
    float mean = s1 * 0.0078125f;
    float var  = fmaf(s2, 0.0078125f, -mean * mean);
    float rs = rsqrtf(var + 1e-5f);
    float vv0 = (u0 - mean) * rs * n1g[lane]      + n1b[lane];
    float vv1 = (u1 - mean) * rs * n1g[lane + 64] + n1b[lane + 64];
    v32[(size_t)node * 128 + lane]      = vv0;
    v32[(size_t)node * 128 + lane + 64] = vv1;
    v16[(size_t)node * 128 + lane]      = f2bf(vv0);
    v16[(size_t)node * 128 + lane + 64] = f2bf(vv1);
  }
}

// ---------- K2: fused FFN: h_Vnew = mask_V * LN2(v + gelu(v@Wgi+bgi)@Wgo+bgo)
__global__ __launch_bounds__(256, 4) void k_ffn(
  const unsigned short* __restrict__ v16,
  const unsigned short* __restrict__ Wtgi, const float* __restrict__ bgi,
  const unsigned short* __restrict__ Wtgo, const float* __restrict__ bgo,
  const float* __restrict__ v32,
  const float* __restrict__ n2g, const float* __restrict__ n2b,
  const float* __restrict__ maskV, float* __restrict__ outV)
{
  __shared__ __align__(16) short Av[2176];    // 16 x 136
  __shared__ __align__(16) short Xb[8320];    // 16 x 520; overlaid by U (16x132 f32)
  float* U = (float*)Xb;
  const int tid = threadIdx.x;
  const int row0 = blockIdx.x * 16;
  const uint2* src = (const uint2*)(v16 + (size_t)row0 * H_DIM);
  for (int i = tid; i < 512; i += 256) {
    int r = i >> 5, c = (i & 31) << 2;
    *(uint2*)&Av[r * 136 + c] = src[i];
  }
  __syncthreads();
  const int wid = tid >> 6, lane = tid & 63;
  const int lr = lane & 15, lg = lane >> 4, kele = lg * 8;
  f32x4 zero = {0.f, 0.f, 0.f, 0.f};
  f32x4 acc[8];
  #pragma unroll
  for (int n = 0; n < 8; ++n) acc[n] = zero;
  #pragma unroll
  for (int kk = 0; kk < 4; ++kk) {
    short8 a = *(const short8*)&Av[lr * 136 + kk * 32 + kele];
    #pragma unroll
    for (int n = 0; n < 8; ++n) {
      short8 bf = *(const short8*)(const void*)(Wtgi + (size_t)(wid * 128 + n * 16 + lr) * 128 + kk * 32 + kele);
      acc[n] = MFMA16(a, bf, acc[n]);
    }
  }
  #pragma unroll
  for (int n = 0; n < 8; ++n) {
    int col = wid * 128 + n * 16 + lr;
    float bb = bgi[col];
    #pragma unroll
    for (int r = 0; r < 4; ++r) {
      int row = lg * 4 + r;
      Xb[row * 520 + col] = (short)cvtpk(gelu_f(acc[n][r] + bb), 0.f);
    }
  }
  __syncthreads();
  f32x4 acc2[2];
  #pragma unroll
  for (int n = 0; n < 2; ++n) acc2[n] = zero;
  #pragma unroll 4
  for (int kk = 0; kk < 16; ++kk) {
    short8 a = *(const short8*)&Xb[lr * 520 + kk * 32 + kele];
    #pragma unroll
    for (int n = 0; n < 2; ++n) {
      short8 bf = *(const short8*)(const void*)(Wtgo + (size_t)(wid * 32 + n * 16 + lr) * 512 + kk * 32 + kele);
      acc2[n] = MFMA16(a, bf, acc2[n]);
    }
  }
  __syncthreads();                  // all Xb reads done before U overlay
  #pragma unroll
  for (int n = 0; n < 2; ++n) {
    int col = wid * 32 + n * 16 + lr;
    float bb = bgo[col];
    #pragma unroll
    for (int r = 0; r < 4; ++r) {
      int row = lg * 4 + r;
      U[row * 132 + col] = acc2[n][r] + bb + v32[(size_t)(row0 + row) * 128 + col];
    }
  }
  __syncthreads();
  if (tid < 128) {
    int r = tid >> 3, sub = tid & 7;
    const float* Ur = &U[r * 132 + sub * 16];
    float u[16]; float s1 = 0.f, s2 = 0.f;
    #pragma unroll
    for (int i = 0; i < 16; ++i) { u[i] = Ur[i]; s1 += u[i]; s2 += u[i] * u[i]; }
    s1 += __shfl_xor(s1, 1); s1 += __shfl_xor(s1, 2); s1 += __shfl_xor(s1, 4);
    s2 += __shfl_xor(s2, 1); s2 += __shfl_xor(s2, 2); s2 += __shfl_xor(s2, 4);
    float mean = s1 * 0.0078125f;
    float var  = fmaf(s2, 0.0078125f, -mean * mean);
    float rs = rsqrtf(var + 1e-5f);
    int nd = row0 + r;
    float mv = maskV[nd];
    float* dst = outV + (size_t)nd * 128 + sub * 16;
    #pragma unroll
    for (int i = 0; i < 16; ++i) {
      int c = sub * 16 + i;
      dst[i] = ((u[i] - mean) * rs * n2g[c] + n2b[c]) * mv;
    }
  }
}

// ---------- K3: edge message MLP + residual + LN3 ----------
__global__ __launch_bounds__(256, 4) void k_edge(
  const float* __restrict__ hE, const int* __restrict__ Eidx,
  const float* __restrict__ hVn,
  const unsigned short* __restrict__ Wt11, const float* __restrict__ b11,
  const unsigned short* __restrict__ Wt12, const float* __restrict__ b12,
  const unsigned short* __restrict__ Wt13, const float* __restrict__ b13,
  const float* __restrict__ n3g, const float* __restrict__ n3b,
  float* __restrict__ outE)
{
  __shared__ __align__(16) short Abuf[13056];
  __shared__ __align__(16) short hvs[128];
  __shared__ __align__(16) float aux[256];   // gamma | beta (staged up front)
  float* MSG = (float*)Abuf;                 // stride 132 floats (layer-3 out)

  const int tid  = threadIdx.x;
  const int node = blockIdx.x;
  const int b    = node >> 11;

  if (tid < 128) {
    aux[tid]       = n3g[tid];
    aux[128 + tid] = n3b[tid];
  }
  if (tid < 32) {
    float4 v = ((const float4*)(hVn + (size_t)node * H_DIM))[tid];
    uint2 p; p.x = cvtpk(v.x, v.y); p.y = cvtpk(v.z, v.w);
    ((uint2*)hvs)[tid] = p;
  }

  const float4* srcE = (const float4*)(hE + (size_t)node * K_NBR * H_DIM);
  #pragma unroll
  for (int ii = 0; ii < 6; ++ii) {
    int i = tid + ii * 256;
    float4 v = srcE[i];
    int r = i >> 5, c = (i & 31) << 2;
    uint2 p; p.x = cvtpk(v.x, v.y); p.y = cvtpk(v.z, v.w);
    *(uint2*)&Abuf[r * 264 + c] = p;
  }
  const int* eip = Eidx + (size_t)node * K_NBR;
  #pragma unroll
  for (int ii = 0; ii < 6; ++ii) {
    int i = tid + ii * 256;
    int r = i >> 5, c = i & 31;
    int e = eip[r];
    float4 v = ((const float4*)(hVn + ((size_t)(b * L_SEQ) + e) * H_DIM))[c];
    uint2 p; p.x = cvtpk(v.x, v.y); p.y = cvtpk(v.z, v.w);
    *(uint2*)&Abuf[r * 264 + 128 + (c << 2)] = p;
  }
  __syncthreads();

  const int wid = tid >> 6, lane = tid & 63;
  const int lr = lane & 15, lg = lane >> 4, kele = lg * 8;

  f32x4 zero = {0.f, 0.f, 0.f, 0.f};
  f32x4 acc[3][2];
  #pragma unroll
  for (int t = 0; t < 3; ++t)
    #pragma unroll
    for (int n = 0; n < 2; ++n) acc[t][n] = zero;

  // ---- layer 1, K=384: 4 broadcast self-kk + 8 staged kk
  #pragma unroll
  for (int kk = 0; kk < 4; ++kk) {
    short8 as = *(const short8*)&hvs[kk * 32 + kele];
    #pragma unroll
    for (int n = 0; n < 2; ++n) {
      short8 bf = *(const short8*)(const void*)(Wt11 + (size_t)(wid * 32 + n * 16 + lr) * 384 + kk * 32 + kele);
      acc[0][n] = MFMA16(as, bf, acc[0][n]);
      acc[1][n] = MFMA16(as, bf, acc[1][n]);
      acc[2][n] = MFMA16(as, bf, acc[2][n]);
    }
  }
  #pragma unroll 2
  for (int kk = 0; kk < 8; ++kk) {
    short8 a0 = *(const short8*)&Abuf[(lr     ) * 264 + kk * 32 + kele];
    short8 a1 = *(const short8*)&Abuf[(lr + 16) * 264 + kk * 32 + kele];
    short8 a2 = *(const short8*)&Abuf[(lr + 32) * 264 + kk * 32 + kele];
    #pragma unroll
    for (int n = 0; n < 2; ++n) {
      short8 bf = *(const short8*)(const void*)(Wt11 + (size_t)(wid * 32 + n * 16 + lr) * 384 + 128 + kk * 32 + kele);
      acc[0][n] = MFMA16(a0, bf, acc[0][n]);
      acc[1][n] = MFMA16(a1, bf, acc[1][n]);
      acc[2][n] = MFMA16(a2, bf, acc[2][n]);
    }
  }
  __syncthreads();
  #pragma unroll
  for (int t = 0; t < 3; ++t)
    #pragma unroll
    for (int n = 0; n < 2; ++n) {
      int col = wid * 32 + n * 16 + lr;
      float bb = b11[col];
      #pragma unroll
      for (int r = 0; r < 4; ++r) {
        int row = t * 16 + lg * 4 + r;
        Abuf[row * 136 + col] = (short)cvtpk(gelu_f(acc[t][n][r] + bb), 0.f);
      }
    }
  __syncthreads();                       // X1 ready

  #pragma unroll
  for (int t = 0; t < 3; ++t)
    #pragma unroll
    for (int n = 0; n < 2; ++n) acc[t][n] = zero;
  #pragma unroll
  for (int kk = 0; kk < 4; ++kk) {
    short8 a0 = *(const short8*)&Abuf[(lr     ) * 136 + kk * 32 + kele];
    short8 a1 = *(const short8*)&Abuf[(lr + 16) * 136 + kk * 32 + kele];
    short8 a2 = *(const short8*)&Abuf[(lr + 32) * 136 + kk * 32 + kele];
    #pragma unroll
    for (int n = 0; n < 2; ++n) {
      short8 bf = *(const short8*)(const void*)(Wt12 + (size_t)(wid * 32 + n * 16 + lr) * 128 + kk * 32 + kele);
      acc[0][n] = MFMA16(a0, bf, acc[0][n]);
      acc[1][n] = MFMA16(a1, bf, acc[1][n]);
      acc[2][n] = MFMA16(a2, bf, acc[2][n]);
    }
  }
  #pragma unroll
  for (int t = 0; t < 3; ++t)
    #pragma unroll
    for (int n = 0; n < 2; ++n) {
      int col = wid * 32 + n * 16 + lr;
      float bb = b12[col];
      #pragma unroll
      for (int r = 0; r < 4; ++r) {
        int row = t * 16 + lg * 4 + r;
        Abuf[6528 + row * 136 + col] = (short)cvtpk(gelu_f(acc[t][n][r] + bb), 0.f);
      }
    }
  __syncthreads();                       // X2 ready

  #pragma unroll
  for (int t = 0; t < 3; ++t)
    #pragma unroll
    for (int n = 0; n < 2; ++n) acc[t][n] = zero;
  #pragma unroll
  for (int kk = 0; kk < 4; ++kk) {
    short8 a0 = *(const short8*)&Abuf[6528 + (lr     ) * 136 + kk * 32 + kele];
    short8 a1 = *(const short8*)&Abuf[6528 + (lr + 16) * 136 + kk * 32 + kele];
    short8 a2 = *(const short8*)&Abuf[6528 + (lr + 32) * 136 + kk * 32 + kele];
    #pragma unroll
    for (int n = 0; n < 2; ++n) {
      short8 bf = *(const short8*)(const void*)(Wt13 + (size_t)(wid * 32 + n * 16 + lr) * 128 + kk * 32 + kele);
      acc[0][n] = MFMA16(a0, bf, acc[0][n]);
      acc[1][n] = MFMA16(a1, bf, acc[1][n]);
      acc[2][n] = MFMA16(a2, bf, acc[2][n]);
    }
  }
  __syncthreads();                       // X2 reads done; region becomes MSG
  #pragma unroll
  for (int t = 0; t < 3; ++t)
    #pragma unroll
    for (int n = 0; n < 2; ++n) {
      int col = wid * 32 + n * 16 + lr;
      float bb = b13[col];
      #pragma unroll
      for (int r = 0; r < 4; ++r) {
        int row = t * 16 + lg * 4 + r;
        MSG[row * 132 + col] = acc[t][n][r] + bb;
      }
    }
  __syncthreads();

  // per-edge residual + LN3: 4 threads per edge row (192 threads)
  if (tid < 192) {
    int rr = tid >> 2, q = tid & 3;
    size_t ebase = ((size_t)node * K_NBR + rr) * H_DIM;
    const float4* he4 = (const float4*)(hE + ebase) + q * 8;
    const float4* m4  = (const float4*)(MSG + rr * 132) + q * 8;
    float s1 = 0.f, s2 = 0.f;
    #pragma unroll
    for (int i = 0; i < 8; ++i) {
      float4 a = he4[i]; float4 mm = m4[i];
      float x0 = a.x + mm.x, x1 = a.y + mm.y, x2 = a.z + mm.z, x3 = a.w + mm.w;
      s1 += x0 + x1 + x2 + x3;
      s2 += x0 * x0 + x1 * x1 + x2 * x2 + x3 * x3;
    }
    s1 += __shfl_xor(s1, 1); s1 += __shfl_xor(s1, 2);
    s2 += __shfl_xor(s2, 1); s2 += __shfl_xor(s2, 2);
    float mean = s1 * 0.0078125f;
    float var  = fmaf(s2, 0.0078125f, -mean * mean);
    float rs = rsqrtf(var + 1e-5f);
    float4* dst = (float4*)(outE + ebase) + q * 8;
    #pragma unroll
    for (int i = 0; i < 8; ++i) {
      float4 a = he4[i]; float4 mm = m4[i];
      int c = q * 32 + i * 4;
      float4 o;
      o.x = (a.x + mm.x - mean) * rs * aux[c + 0] + aux[128 + c + 0];
      o.y = (a.y + mm.y - mean) * rs * aux[c + 1] + aux[128 + c + 1];
      o.z = (a.z + mm.z - mean) * rs * aux[c + 2] + aux[128 + c + 2];
      o.w = (a.w + mm.w - mean) * rs * aux[c + 3] + aux[128 + c + 3];
      dst[i] = o;
    }
  }
}

extern "C" void kernel_launch(void* const* d_in, const int* in_sizes, int n_in,
                              void* d_out, int out_size, void* d_ws, size_t ws_size,
                              hipStream_t stream) {
  const float* hV   = (const float*)d_in[0];
  const float* hE   = (const float*)d_in[1];
  const int*   Eidx = (const int*)d_in[2];
  const float* maskV= (const float*)d_in[3];
  const float* maskA= (const float*)d_in[4];
  const float* W1 = (const float*)d_in[5];  const float* b1 = (const float*)d_in[6];
  const float* W2 = (const float*)d_in[7];  const float* b2 = (const float*)d_in[8];
  const float* W3 = (const float*)d_in[9];  const float* b3 = (const float*)d_in[10];
  const float* W11= (const float*)d_in[11]; const float* b11= (const float*)d_in[12];
  const float* W12= (const float*)d_in[13]; const float* b12= (const float*)d_in[14];
  const float* W13= (const float*)d_in[15]; const float* b13= (const float*)d_in[16];
  const float* Wgi= (const float*)d_in[17]; const float* bgi= (const float*)d_in[18];
  const float* Wgo= (const float*)d_in[19]; const float* bgo= (const float*)d_in[20];
  const float* n1g= (const float*)d_in[21]; const float* n1b= (const float*)d_in[22];
  const float* n2g= (const float*)d_in[23]; const float* n2b= (const float*)d_in[24];
  const float* n3g= (const float*)d_in[25]; const float* n3b= (const float*)d_in[26];

  float* outV = (float*)d_out;
  float* outE = outV + (size_t)4 * 2048 * 128;   // h_E output region

  // d_ws: transposed bf16 weights only (~590 KB) — read during k_edge, so
  // must be outside the h_E output region.
  unsigned short* wsu  = (unsigned short*)d_ws;
  unsigned short* Wt1  = wsu + 0;
  unsigned short* Wt2  = wsu + 49152;
  unsigned short* Wt3  = wsu + 65536;
  unsigned short* Wt11 = wsu + 81920;
  unsigned short* Wt12 = wsu + 131072;
  unsigned short* Wt13 = wsu + 147456;
  unsigned short* Wtgi = wsu + 163840;
  unsigned short* Wtgo = wsu + 229376;

  // large intermediates live in the not-yet-written h_E output region
  // (all dead before k_edge starts writing it)
  char* scr = (char*)outE;
  unsigned short* hV16 = (unsigned short*)scr;                     // 2 MB
  float*          v32  = (float*)(scr + (size_t)2097152);          // 4 MB
  unsigned short* v16  = (unsigned short*)(scr + (size_t)6291456); // 2 MB

  k_wt<<<192, 256, 0, stream>>>(W1,  Wt1,  384, 128);
  k_wt<<<64,  256, 0, stream>>>(W2,  Wt2,  128, 128);
  k_wt<<<64,  256, 0, stream>>>(W3,  Wt3,  128, 128);
  k_wt<<<192, 256, 0, stream>>>(W11, Wt11, 384, 128);
  k_wt<<<64,  256, 0, stream>>>(W12, Wt12, 128, 128);
  k_wt<<<64,  256, 0, stream>>>(W13, Wt13, 128, 128);
  k_wt<<<256, 256, 0, stream>>>(Wgi, Wtgi, 128, 512);
  k_wt<<<256, 256, 0, stream>>>(Wgo, Wtgo, 512, 128);
  k_cvt16<<<1024, 256, 0, stream>>>(hV, hV16);

  k_node<<<8192, 256, 0, stream>>>(hV, hE, hV16, Eidx, maskA,
                                   Wt1, b1, Wt2, b2, Wt3, b3, n1g, n1b, v32, v16);
  k_ffn<<<512, 256, 0, stream>>>(v16, Wtgi, bgi, Wtgo, bgo, v32,
                                 n2g, n2b, maskV, outV);
  k_edge<<<8192, 256, 0, stream>>>(hE, Eidx, outV,
                                   Wt11, b11, Wt12, b12, Wt13, b13, n3g, n3b, outE);
}